// Round 2
// baseline (884.247 us; speedup 1.0000x reference)
//
#include <hip/hip_runtime.h>

// ReLU on 16384x8192 fp32 — pure HBM-streaming kernel.
// Design (unchanged from R0 — never measured due to broker timeouts):
//   1. Grid-stride loop, capped grid: 2048 blocks x 256 thr = 8 blocks/CU on
//      256 CUs, 32 waves/CU (full occupancy). Stride = 524,288 float4s;
//      trip count = exactly 64 for this shape, uniform across threads.
//   2. Non-temporal loads/stores: 1 GiB zero-reuse stream should not thrash
//      L2 (32 MiB) / L3 (256 MiB).
//   3. #pragma unroll 4 gives 4 independent load/store pairs in flight per
//      wave for memory-level parallelism.
// Roofline: 1.074 GB mandatory traffic / 6.29 TB/s achievable = ~171 us floor.

typedef float f32x4 __attribute__((ext_vector_type(4)));

__global__ __launch_bounds__(256) void relu_f32x4_gs(
    const f32x4* __restrict__ in, f32x4* __restrict__ out, long long n4) {
  const long long stride = (long long)gridDim.x * blockDim.x;
  const long long tid = (long long)blockIdx.x * blockDim.x + threadIdx.x;

  // Full iterations are uniform across all threads (no divergence in hot loop).
  const long long full = n4 / stride;
  long long idx = tid;

#pragma unroll 4
  for (long long it = 0; it < full; ++it) {
    f32x4 v = __builtin_nontemporal_load(&in[idx]);
    v.x = fmaxf(v.x, 0.0f);
    v.y = fmaxf(v.y, 0.0f);
    v.z = fmaxf(v.z, 0.0f);
    v.w = fmaxf(v.w, 0.0f);
    __builtin_nontemporal_store(v, &out[idx]);
    idx += stride;
  }

  // Remainder (n4 % stride threads do one extra element). Zero for this shape.
  if (idx < n4) {
    f32x4 v = __builtin_nontemporal_load(&in[idx]);
    v.x = fmaxf(v.x, 0.0f);
    v.y = fmaxf(v.y, 0.0f);
    v.z = fmaxf(v.z, 0.0f);
    v.w = fmaxf(v.w, 0.0f);
    __builtin_nontemporal_store(v, &out[idx]);
  }
}

// Scalar tail for n not divisible by 4 (zero-sized for this shape).
__global__ void relu_f32_tail_kernel(
    const float* __restrict__ in, float* __restrict__ out,
    long long start, long long n) {
  long long i = start + (long long)blockIdx.x * blockDim.x + threadIdx.x;
  if (i < n) {
    out[i] = fmaxf(in[i], 0.0f);
  }
}

extern "C" void kernel_launch(void* const* d_in, const int* in_sizes, int n_in,
                              void* d_out, int out_size, void* d_ws, size_t ws_size,
                              hipStream_t stream) {
  const float* in = (const float*)d_in[0];
  float* out = (float*)d_out;
  long long n = (long long)in_sizes[0];  // 134,217,728 elements
  long long n4 = n / 4;                  // 33,554,432 float4s

  const int block = 256;
  // Cap at 2048 blocks: 8 blocks/CU x 256 CU, 32 waves/CU (max occupancy).
  long long blocks_needed = (n4 + block - 1) / block;
  unsigned grid = (unsigned)(blocks_needed < 2048 ? blocks_needed : 2048);
  if (grid == 0) grid = 1;

  relu_f32x4_gs<<<grid, block, 0, stream>>>(
      (const f32x4*)in, (f32x4*)out, n4);

  long long tail_start = n4 * 4;
  long long tail = n - tail_start;  // 0 for this shape, but stay correct
  if (tail > 0) {
    relu_f32_tail_kernel<<<1, 64, 0, stream>>>(in, out, tail_start, n);
  }
}

// Round 3
// 876.983 us; speedup vs baseline: 1.0083x; 1.0083x over previous
//
#include <hip/hip_runtime.h>

// ReLU on 16384x8192 fp32 — pure HBM-streaming kernel.
// R2 evidence: harness dur_us (884) includes ~686 us of harness poison-fills
// (2x 2.147GB fillBufferAligned @ 6.3 TB/s, seen in rocprof). The relu kernel
// itself is <334 us (absent from top-5), inferred ~198 us = 5.4 TB/s.
// This round: close the 5.4 -> 6.29 TB/s gap (m13 float4-copy ceiling).
//   - Hand-batched 4-wide pipeline: 4 independent coalesced float4 loads
//     issued before any dependent store, guaranteeing 4 outstanding loads
//     per wave at the stall point (compiler-proof MLP).
//   - Plain (cache-default) loads/stores, matching the m13 copy ubench that
//     achieved 6.29 TB/s on the identical read+write access mix.
//   - Grid: 2048 blocks x 256 thr = 8 blocks/CU, 32 waves/CU full occupancy.
//     stride = 524,288 float4s; batched trip count = 33,554,432/(4*524,288)
//     = exactly 16, uniform across all threads; remainder loop generic.

typedef float f32x4 __attribute__((ext_vector_type(4)));

__device__ __forceinline__ f32x4 relu4(f32x4 v) {
  v.x = fmaxf(v.x, 0.0f);
  v.y = fmaxf(v.y, 0.0f);
  v.z = fmaxf(v.z, 0.0f);
  v.w = fmaxf(v.w, 0.0f);
  return v;
}

__global__ __launch_bounds__(256) void relu_f32x4_gs(
    const f32x4* __restrict__ in, f32x4* __restrict__ out, long long n4) {
  const long long stride = (long long)gridDim.x * blockDim.x;
  const long long tid = (long long)blockIdx.x * blockDim.x + threadIdx.x;
  const long long stride4 = 4 * stride;

  // Batched full iterations: uniform trip count, no divergence.
  const long long nfull = n4 / stride4;  // 16 for this shape
  long long i = tid;

  for (long long it = 0; it < nfull; ++it, i += stride4) {
    // 4 independent coalesced loads issued back-to-back (4x MLP per wave).
    f32x4 v0 = in[i];
    f32x4 v1 = in[i + stride];
    f32x4 v2 = in[i + 2 * stride];
    f32x4 v3 = in[i + 3 * stride];
    out[i]              = relu4(v0);
    out[i + stride]     = relu4(v1);
    out[i + 2 * stride] = relu4(v2);
    out[i + 3 * stride] = relu4(v3);
  }

  // Generic remainder: singles at grid stride (zero iterations for this shape).
  for (long long j = nfull * stride4 + tid; j < n4; j += stride) {
    out[j] = relu4(in[j]);
  }
}

// Scalar tail for n not divisible by 4 (zero-sized for this shape).
__global__ void relu_f32_tail_kernel(
    const float* __restrict__ in, float* __restrict__ out,
    long long start, long long n) {
  long long i = start + (long long)blockIdx.x * blockDim.x + threadIdx.x;
  if (i < n) {
    out[i] = fmaxf(in[i], 0.0f);
  }
}

extern "C" void kernel_launch(void* const* d_in, const int* in_sizes, int n_in,
                              void* d_out, int out_size, void* d_ws, size_t ws_size,
                              hipStream_t stream) {
  const float* in = (const float*)d_in[0];
  float* out = (float*)d_out;
  long long n = (long long)in_sizes[0];  // 134,217,728 elements
  long long n4 = n / 4;                  // 33,554,432 float4s

  const int block = 256;
  // 2048 blocks: 8 blocks/CU x 256 CU, 32 waves/CU (max occupancy).
  long long blocks_needed = (n4 + block - 1) / block;
  unsigned grid = (unsigned)(blocks_needed < 2048 ? blocks_needed : 2048);
  if (grid == 0) grid = 1;

  relu_f32x4_gs<<<grid, block, 0, stream>>>(
      (const f32x4*)in, (f32x4*)out, n4);

  long long tail_start = n4 * 4;
  long long tail = n - tail_start;  // 0 for this shape, but stay correct
  if (tail > 0) {
    relu_f32_tail_kernel<<<1, 64, 0, stream>>>(in, out, tail_start, n);
  }
}